// Round 3
// baseline (385.096 us; speedup 1.0000x reference)
//
#include <hip/hip_runtime.h>
#include <hip/hip_bf16.h>
#include <stdint.h>

#define G_ 8
#define T_ 1024
#define K_ 7168
#define N_ 2048
#define KB_ (K_/128)   // 56
#define NB_ (N_/128)   // 16
#define NT_ (K_/64)    // 112 K-tiles

typedef __attribute__((ext_vector_type(4))) float f32x4;
typedef __attribute__((ext_vector_type(2))) float f32x2;
typedef __attribute__((ext_vector_type(8))) short bf16x8;

typedef __attribute__((address_space(3))) uint32_t lds_u32_t;
typedef const __attribute__((address_space(1))) uint32_t gbl_u32_t;

__device__ __forceinline__ void gload_lds16(const void* gsrc, const void* ldst)
{
    __builtin_amdgcn_global_load_lds(
        (gbl_u32_t*)(uintptr_t)gsrc,
        (lds_u32_t*)(uint32_t)(uintptr_t)ldst, 16, 0, 0);
}

__device__ __forceinline__ void blockbar()
{
    asm volatile("" ::: "memory");
    __builtin_amdgcn_s_barrier();
    asm volatile("" ::: "memory");
}

// ---------------------------------------------------------------------------
// Kernel 1: activation quantize->dequantize -> bf16 (per (token,128) amax/448)
// ---------------------------------------------------------------------------
__global__ __launch_bounds__(256) void act_quant_kernel(
    const float* __restrict__ xs, __hip_bfloat16* __restrict__ xq)
{
    const int grp = (blockIdx.x * 256 + threadIdx.x) >> 5;
    const int l   = threadIdx.x & 31;
    const size_t base = (size_t)grp * 128 + (size_t)l * 4;

    const float4 v = *(const float4*)(xs + base);
    float am = fmaxf(fmaxf(fabsf(v.x), fabsf(v.y)), fmaxf(fabsf(v.z), fabsf(v.w)));
#pragma unroll
    for (int off = 1; off <= 16; off <<= 1)
        am = fmaxf(am, __shfl_xor(am, off, 64));
    const float s = am / 448.0f;

    const int pk01 = __builtin_amdgcn_cvt_pk_fp8_f32(v.x / s, v.y / s, 0, false);
    const int pk23 = __builtin_amdgcn_cvt_pk_fp8_f32(v.z / s, v.w / s, 0, false);
    const f32x2 d01 = __builtin_amdgcn_cvt_pk_f32_fp8(pk01, false);
    const f32x2 d23 = __builtin_amdgcn_cvt_pk_f32_fp8(pk23, false);

    union { uint2 u; __hip_bfloat16 h[4]; } p;
    p.h[0] = __float2bfloat16(d01[0] * s);
    p.h[1] = __float2bfloat16(d01[1] * s);
    p.h[2] = __float2bfloat16(d23[0] * s);
    p.h[3] = __float2bfloat16(d23[1] * s);
    *(uint2*)(xq + base) = p.u;
}

// ---------------------------------------------------------------------------
// Kernel 2: 256x256-tile 8-wave 4-phase bf16 GEMM with FUSED weight dequant.
//   A (xq bf16): global_load_lds width-16, pre-swizzled source.
//   B (w fp32 codes): T14 reg-staging — loads issued ph1, *scale -> bf16 ->
//   swizzled ds_write at ph4 under MFMA Q11. vmcnt(4) at ph4 drains both
//   B-regs(u+2) and A-glds(u+1).
// ---------------------------------------------------------------------------
#define MFMA_Q(MH, NH)                                                        \
  { _Pragma("unroll") for (int m = 0; m < 4; ++m) {                           \
      _Pragma("unroll") for (int n = 0; n < 2; ++n) {                         \
        _Pragma("unroll") for (int ks = 0; ks < 2; ++ks) {                    \
          acc[(MH)*4+m][(NH)*2+n] = __builtin_amdgcn_mfma_f32_16x16x32_bf16(  \
              bA[m*2+ks], bB[((NH)*2+n)*2+ks], acc[(MH)*4+m][(NH)*2+n],       \
              0, 0, 0);                                                       \
  } } } }

#define LDA(m, ks, MH, b)                                                     \
  bA[(m)*2+(ks)] = *(const bf16x8*)(smem + (b)*32768 +                        \
      (wrow + (MH)*64 + (m)*16 + l15)*128 + colK[ks])

#define LDB(n, ks, b)                                                         \
  bB[(n)*2+(ks)] = *(const bf16x8*)(smem + 65536 + (b)*32768 +                \
      (wcol + (n)*16 + l15)*128 + colK[ks])

#define STG_A(c, t, b) gload_lds16(pA[c] + (size_t)(t)*64,                    \
      smem + (b)*32768 + (c)*8192 + dstw)

// issue 8 fp32 code loads (32B/thread) for B rows {c*64+row0}, k-tile t
#define LOAD_B(t)                                                             \
  { _Pragma("unroll") for (int c = 0; c < 4; ++c) {                           \
      const float* s_ = pW[c] + (size_t)(t) * 64;                             \
      br[c*2]   = *(const f32x4*)(s_);                                        \
      br[c*2+1] = *(const f32x4*)(s_ + 4);                                    \
  } }

// convert + swizzled ds_write of the 4 staged rows into buf b
#define WRITE_B(t, b)                                                         \
  { const int kb_ = (t) >> 1;                                                 \
    const float s0_ = scale[scb + kb_];                                       \
    const float s1_ = scale[scb + KB_ + kb_];                                 \
    _Pragma("unroll") for (int c = 0; c < 4; ++c) {                           \
      const float sc_ = (c < 2) ? s0_ : s1_;                                  \
      union { __hip_bfloat16 h[8]; bf16x8 v; } u_;                            \
      _Pragma("unroll") for (int e = 0; e < 4; ++e) {                         \
        u_.h[e]     = __float2bfloat16(br[c*2][e]   * sc_);                   \
        u_.h[e + 4] = __float2bfloat16(br[c*2+1][e] * sc_);                   \
      }                                                                       \
      *(bf16x8*)(smem + 65536 + (b)*32768 + (c*64 + brow)*128 + bslot) = u_.v;\
  } }

__global__ __launch_bounds__(512) void gemm8_kernel(
    const __hip_bfloat16* __restrict__ xq, const float* __restrict__ w,
    const float* __restrict__ scale, const float* __restrict__ bias,
    float* __restrict__ y)
{
    __shared__ char smem[131072];

    const int bx0 = blockIdx.x;
    const int bx  = (bx0 & 7) * 32 + (bx0 >> 3);   // XCD swizzle (256 % 8 == 0)
    const int g   = bx >> 5;
    const int tm  = (bx >> 3) & 3;
    const int tn  = bx & 7;
    const int t0  = tm * 256, n0 = tn * 256;

    const int tid = threadIdx.x, lane = tid & 63, wid = tid >> 6;
    const int l15 = lane & 15, lhi = lane >> 4;
    const int wrow = (wid >> 2) * 128;
    const int wcol = (wid & 3) * 64;

    const __hip_bfloat16* Ag = xq + (size_t)g * T_ * K_;
    const float*          Wg = w  + (size_t)g * N_ * K_;

    // A staging: LDS (row = c*64 + tid/8, slot = tid%8) <- global slot^row&7
    const int srow = tid >> 3;
    const int xoff = ((tid & 7) ^ (srow & 7)) * 8;
    const __hip_bfloat16* pA[4];
#pragma unroll
    for (int c = 0; c < 4; ++c)
        pA[c] = Ag + (size_t)(t0 + c * 64 + srow) * K_ + xoff;
    const int dstw = wid * 1024;

    // B reg-staging: thread owns rows {c*64 + tid/8}, global slot tid%7..
    const int brow  = tid >> 3;            // 0..63
    const int gslot = tid & 7;
    const int bslot = (gslot ^ (brow & 7)) * 16;   // swizzled byte slot
    const float* pW[4];
#pragma unroll
    for (int c = 0; c < 4; ++c)
        pW[c] = Wg + (size_t)(n0 + c * 64 + brow) * K_ + gslot * 8;
    const int scb = ((size_t)g * NB_ + tn * 2) * KB_;   // scale base (uniform)

    // frag-read byte-column offsets with matching XOR swizzle
    const int rxor = (l15 & 7) << 4;
    int colK[2];
    colK[0] = (lhi * 16) ^ rxor;
    colK[1] = (64 + lhi * 16) ^ rxor;

    f32x4 acc[8][4] = {};
    bf16x8 bA[8], bB[8];
    f32x4 br[8];

    // ---- prologue: tiles 0 -> buf0, 1 -> buf1 ----
    LOAD_B(0);
#pragma unroll
    for (int c = 0; c < 4; ++c) STG_A(c, 0, 0);
    asm volatile("s_waitcnt vmcnt(4)" ::: "memory");   // B-regs(0) landed
    WRITE_B(0, 0);
    LOAD_B(1);
#pragma unroll
    for (int c = 0; c < 4; ++c) STG_A(c, 1, 1);
    asm volatile("s_waitcnt vmcnt(4)" ::: "memory");   // B-regs(1) landed
    WRITE_B(1, 1);
    asm volatile("s_waitcnt vmcnt(0) lgkmcnt(0)" ::: "memory");
    blockbar();

    for (int u = 0; u < NT_; ++u) {
        const int cb = u & 1;
        const bool pf = (u + 2 < NT_);

        // ---- ph1: issue B-loads(u+2); read A-half0 + B n0,n1 ----
        if (pf) LOAD_B(u + 2);
        LDA(0,0,0,cb); LDA(0,1,0,cb); LDA(1,0,0,cb); LDA(1,1,0,cb);
        LDA(2,0,0,cb); LDA(2,1,0,cb); LDA(3,0,0,cb); LDA(3,1,0,cb);
        LDB(0,0,cb);   LDB(0,1,cb);   LDB(1,0,cb);   LDB(1,1,cb);
        blockbar();
        asm volatile("s_waitcnt lgkmcnt(0)" ::: "memory");
        __builtin_amdgcn_s_setprio(1);
        MFMA_Q(0, 0);
        __builtin_amdgcn_s_setprio(0);
        blockbar();

        // ---- ph2: read B n2,n3; stage A-even(u+2) ----
        LDB(2,0,cb); LDB(2,1,cb); LDB(3,0,cb); LDB(3,1,cb);
        if (pf) { STG_A(0, u+2, cb); STG_A(2, u+2, cb); }
        blockbar();
        asm volatile("s_waitcnt lgkmcnt(0)" ::: "memory");
        __builtin_amdgcn_s_setprio(1);
        MFMA_Q(0, 1);
        __builtin_amdgcn_s_setprio(0);
        blockbar();

        // ---- ph3: read A-half1; stage A-odd(u+2) ----
        LDA(0,0,1,cb); LDA(0,1,1,cb); LDA(1,0,1,cb); LDA(1,1,1,cb);
        LDA(2,0,1,cb); LDA(2,1,1,cb); LDA(3,0,1,cb); LDA(3,1,1,cb);
        if (pf) { STG_A(1, u+2, cb); STG_A(3, u+2, cb); }
        blockbar();
        asm volatile("s_waitcnt lgkmcnt(0)" ::: "memory");
        __builtin_amdgcn_s_setprio(1);
        MFMA_Q(1, 0);
        __builtin_amdgcn_s_setprio(0);
        blockbar();

        // ---- ph4: drain B-regs + A(u+1); cvt+write B(u+2); MFMA Q11 ----
        if (pf) {
            asm volatile("s_waitcnt vmcnt(4)" ::: "memory");
            WRITE_B(u + 2, cb);
        } else if (u + 1 < NT_) {
            asm volatile("s_waitcnt vmcnt(0)" ::: "memory");
        }
        __builtin_amdgcn_s_setprio(1);
        MFMA_Q(1, 1);
        __builtin_amdgcn_s_setprio(0);
        blockbar();
    }

    // ---- epilogue: C/D layout col = lane&15, row = (lane>>4)*4 + j ----
    float* Yg = y + (size_t)g * T_ * N_;
#pragma unroll
    for (int n = 0; n < 4; ++n) {
        const int col = n0 + wcol + n * 16 + l15;
        const float bv = bias[g * N_ + col];
#pragma unroll
        for (int m = 0; m < 8; ++m) {
            const int r0 = t0 + wrow + m * 16 + lhi * 4;
#pragma unroll
            for (int j = 0; j < 4; ++j)
                Yg[(size_t)(r0 + j) * N_ + col] = acc[m][n][j] + bv;
        }
    }
}

// ---------------------------------------------------------------------------
extern "C" void kernel_launch(void* const* d_in, const int* in_sizes, int n_in,
                              void* d_out, int out_size, void* d_ws, size_t ws_size,
                              hipStream_t stream)
{
    const float* xs     = (const float*)d_in[0];
    const float* weight = (const float*)d_in[1];
    const float* scale  = (const float*)d_in[2];
    const float* bias   = (const float*)d_in[3];
    float* y = (float*)d_out;

    __hip_bfloat16* xq = (__hip_bfloat16*)d_ws;   // G*T*K bf16 = 117.4 MB

    act_quant_kernel<<<(G_ * T_ * KB_) / 8, 256, 0, stream>>>(xs, xq);
    gemm8_kernel<<<256, 512, 0, stream>>>(xq, weight, scale, bias, y);
}

// Round 4
// 373.166 us; speedup vs baseline: 1.0320x; 1.0320x over previous
//
#include <hip/hip_runtime.h>
#include <hip/hip_bf16.h>
#include <stdint.h>

#define G_ 8
#define T_ 1024
#define K_ 7168
#define N_ 2048
#define KB_ (K_/128)   // 56
#define NB_ (N_/128)   // 16
#define NT8_ 56        // K-tiles of 128

typedef __attribute__((ext_vector_type(4))) float f32x4;
typedef __attribute__((ext_vector_type(8))) int   i32x8;

typedef __attribute__((address_space(3))) uint32_t lds_u32_t;
typedef const __attribute__((address_space(1))) uint32_t gbl_u32_t;

__device__ __forceinline__ void gload_lds16(const void* gsrc, const void* ldst)
{
    __builtin_amdgcn_global_load_lds(
        (gbl_u32_t*)(uintptr_t)gsrc,
        (lds_u32_t*)(uint32_t)(uintptr_t)ldst, 16, 0, 0);
}

__device__ __forceinline__ void blockbar()
{
    asm volatile("" ::: "memory");
    __builtin_amdgcn_s_barrier();
    asm volatile("" ::: "memory");
}

// ---------------------------------------------------------------------------
// Kernel 1: activation quant -> fp8 code bytes + scale table.
//   scale layout: [g][tb=t>>8][kb][t&255] so a (256-token, 1-kb) slice is 1KB
//   contiguous and an 8-kb chunk is 8KB contiguous.
// ---------------------------------------------------------------------------
__global__ __launch_bounds__(256) void act_quant_kernel(
    const float* __restrict__ xs, uint8_t* __restrict__ xq8,
    float* __restrict__ ascale)
{
    const int grp = (blockIdx.x * 256 + threadIdx.x) >> 5;   // quant-block id
    const int l   = threadIdx.x & 31;
    const size_t base = (size_t)grp * 128 + (size_t)l * 4;

    const float4 v = *(const float4*)(xs + base);
    float am = fmaxf(fmaxf(fabsf(v.x), fabsf(v.y)), fmaxf(fabsf(v.z), fabsf(v.w)));
#pragma unroll
    for (int off = 1; off <= 16; off <<= 1)
        am = fmaxf(am, __shfl_xor(am, off, 64));
    const float s = am / 448.0f;

    int pk = __builtin_amdgcn_cvt_pk_fp8_f32(v.x / s, v.y / s, 0, false);
    pk     = __builtin_amdgcn_cvt_pk_fp8_f32(v.z / s, v.w / s, pk, true);
    *(uint32_t*)(xq8 + base) = (uint32_t)pk;

    if (l == 0) {
        const int kb = grp % KB_;
        const int t  = (grp / KB_) & (T_ - 1);
        const int g  = grp / (KB_ * T_);
        ascale[(((size_t)(g * 4 + (t >> 8))) * KB_ + kb) * 256 + (t & 255)] = s;
    }
}

// ---------------------------------------------------------------------------
// Kernel 2: weight recode fp32-held-fp8-codes -> fp8 bytes (exact, no scale)
// ---------------------------------------------------------------------------
__global__ __launch_bounds__(256) void wrecode_kernel(
    const float* __restrict__ w, uint8_t* __restrict__ wq8)
{
    const size_t i = ((size_t)blockIdx.x * 256 + threadIdx.x) * 16;
    uint32_t o[4];
#pragma unroll
    for (int q = 0; q < 4; ++q) {
        const float4 a = *(const float4*)(w + i + q * 4);
        int pk = __builtin_amdgcn_cvt_pk_fp8_f32(a.x, a.y, 0, false);
        pk     = __builtin_amdgcn_cvt_pk_fp8_f32(a.z, a.w, pk, true);
        o[q] = (uint32_t)pk;
    }
    *(uint4*)(wq8 + i) = make_uint4(o[0], o[1], o[2], o[3]);
}

// ---------------------------------------------------------------------------
// Kernel 3: blockwise-fp8 grouped GEMM, 256x256 tile, BK=128, 8 waves,
//   4-phase pipelined, mfma_scale_f32_16x16x128_f8f6f4 with unit scales,
//   per-128-block fp32 rescale into master acc.
//   LDS: A[2][256][128B] (64K) + B (64K) + scales 2x8KB = 144KB.
// ---------------------------------------------------------------------------
union Frag { i32x8 v; struct { int4 lo, hi; } p; };

#define RD_A(mh)                                                              \
  { _Pragma("unroll") for (int m = 0; m < 4; ++m) {                           \
      const int r  = wrow + ((mh)*4 + m)*16 + l15;                            \
      const int rx = (r & 7) << 4;                                            \
      const char* bp = smem + cb*32768 + r*128;                               \
      aF[m].p.lo = *(const int4*)(bp + ((lhi*32) ^ rx));                      \
      aF[m].p.hi = *(const int4*)(bp + ((lhi*32 + 16) ^ rx));                 \
      const float4 sv = *(const float4*)(smem + 131072 + ((u>>3)&1)*8192 +    \
          (u & 7)*1024 + (wrow + ((mh)*4 + m)*16 + lhi*4)*4);                 \
      asw[m][0] = sv.x*wsc; asw[m][1] = sv.y*wsc;                             \
      asw[m][2] = sv.z*wsc; asw[m][3] = sv.w*wsc;                             \
  } }

#define RD_B(nh)                                                              \
  { _Pragma("unroll") for (int n = 0; n < 2; ++n) {                           \
      const int r  = wcol + ((nh)*2 + n)*16 + l15;                            \
      const int rx = (r & 7) << 4;                                            \
      const char* bp = smem + 65536 + cb*32768 + r*128;                       \
      bF[(nh)*2+n].p.lo = *(const int4*)(bp + ((lhi*32) ^ rx));               \
      bF[(nh)*2+n].p.hi = *(const int4*)(bp + ((lhi*32 + 16) ^ rx));          \
  } }

#define MM(mh, nh)                                                            \
  { _Pragma("unroll") for (int m = 0; m < 4; ++m) {                           \
      _Pragma("unroll") for (int n = 0; n < 2; ++n) {                         \
        f32x4 blk = __builtin_amdgcn_mfma_scale_f32_16x16x128_f8f6f4(         \
            aF[m].v, bF[(nh)*2+n].v, z4, 0, 0,                                \
            0, 0x7F7F7F7F, 0, 0x7F7F7F7F);                                    \
        _Pragma("unroll") for (int j = 0; j < 4; ++j)                         \
          acc[(mh)*4+m][(nh)*2+n][j] += blk[j] * asw[m][j];                   \
  } } }

#define STG_A8(c, t, b) gload_lds16(pA8[c] + (size_t)(t)*128,                 \
      smem + (b)*32768 + (c)*8192 + tid*16)
#define STG_B8(c, t, b) gload_lds16(pB8[c] + (size_t)(t)*128,                 \
      smem + 65536 + (b)*32768 + (c)*8192 + tid*16)
#define STG_S(c) gload_lds16(pS + (size_t)(c)*2048,                           \
      smem + 131072 + ((c)&1)*8192 + tid*16)

__global__ __launch_bounds__(512) void gemm_fp8_kernel(
    const uint8_t* __restrict__ xq8, const uint8_t* __restrict__ wq8,
    const float* __restrict__ ascale, const float* __restrict__ wscale,
    const float* __restrict__ bias, float* __restrict__ y)
{
    __shared__ char smem[147456];

    const int bx0 = blockIdx.x;
    const int bx  = (bx0 & 7) * 32 + (bx0 >> 3);   // XCD swizzle
    const int g   = bx >> 5;
    const int tm  = (bx >> 3) & 3;
    const int tn  = bx & 7;
    const int t0  = tm * 256, n0 = tn * 256;

    const int tid = threadIdx.x, lane = tid & 63, wid = tid >> 6;
    const int l15 = lane & 15, lhi = lane >> 4;
    const int wrow = (wid >> 2) * 128;
    const int wcol = (wid & 3) * 64;

    const uint8_t* Ag = xq8 + (size_t)g * T_ * K_;
    const uint8_t* Bg = wq8 + (size_t)g * N_ * K_;

    // staging maps: LDS (row = c*64 + tid/8, slot16 = tid%8) <- global
    // slot16 ^ (row&7); 8KB per call (512 thr x 16B)
    const int srow = tid >> 3;
    const int xoff = ((tid & 7) ^ (srow & 7)) * 16;
    const uint8_t* pA8[4];
    const uint8_t* pB8[4];
#pragma unroll
    for (int c = 0; c < 4; ++c) {
        pA8[c] = Ag + (size_t)(t0 + c * 64 + srow) * K_ + xoff;
        pB8[c] = Bg + (size_t)(n0 + c * 64 + srow) * K_ + xoff;
    }
    const float* pS = ascale + ((size_t)(g * 4 + tm) * KB_) * 256 + tid * 4;
    const int wscb = (g * NB_ + ((n0 + wcol) >> 7)) * KB_;

    const f32x4 z4 = {0.f, 0.f, 0.f, 0.f};
    f32x4 acc[8][4] = {};
    Frag aF[4], bF[4];
    float asw[4][4];

    // ---- prologue: scale chunk 0, tile 0 -> buf0, tile 1 -> buf1 ----
    STG_S(0);
#pragma unroll
    for (int c = 0; c < 4; ++c) { STG_A8(c, 0, 0); STG_B8(c, 0, 0); }
#pragma unroll
    for (int c = 0; c < 4; ++c) { STG_A8(c, 1, 1); STG_B8(c, 1, 1); }
    asm volatile("s_waitcnt vmcnt(8)" ::: "memory");   // S0 + tile0 landed
    blockbar();

    for (int u = 0; u < NT8_; ++u) {
        const int cb = u & 1;
        const bool pf = (u + 2 < NT8_);
        const float wsc = wscale[wscb + u];

        // ---- ph1: [scale chunk]; read A m0-3 (+scales) and B n0-1 ----
        if ((u & 7) == 0 && u + 8 < NT8_) STG_S((u >> 3) + 1);
        RD_A(0); RD_B(0);
        blockbar();
        asm volatile("s_waitcnt lgkmcnt(0)" ::: "memory");
        __builtin_amdgcn_s_setprio(1);
        MM(0, 0);
        __builtin_amdgcn_s_setprio(0);
        blockbar();

        // ---- ph2: read B n2-3; stage A c0,c2 (rows read in ph1) ----
        RD_B(1);
        if (pf) { STG_A8(0, u + 2, cb); STG_A8(2, u + 2, cb); }
        blockbar();
        asm volatile("s_waitcnt lgkmcnt(0)" ::: "memory");
        __builtin_amdgcn_s_setprio(1);
        MM(0, 1);
        __builtin_amdgcn_s_setprio(0);
        blockbar();

        // ---- ph3: read A m4-7 (+scales); stage B c0,c1 (read by ph2) ----
        RD_A(1);
        if (pf) { STG_B8(0, u + 2, cb); STG_B8(1, u + 2, cb); }
        blockbar();
        asm volatile("s_waitcnt lgkmcnt(0)" ::: "memory");
        __builtin_amdgcn_s_setprio(1);
        MM(1, 0);
        __builtin_amdgcn_s_setprio(0);
        blockbar();

        // ---- ph4: stage A c1,c3 + B c2,c3; MFMA; counted drain ----
        if (pf) { STG_A8(1, u + 2, cb); STG_A8(3, u + 2, cb);
                  STG_B8(2, u + 2, cb); STG_B8(3, u + 2, cb); }
        __builtin_amdgcn_s_setprio(1);
        MM(1, 1);
        __builtin_amdgcn_s_setprio(0);
        if (pf)                  asm volatile("s_waitcnt vmcnt(8)" ::: "memory");
        else if (u + 1 < NT8_)   asm volatile("s_waitcnt vmcnt(0)" ::: "memory");
        blockbar();
    }

    // ---- epilogue: C/D layout col = lane&15, row = (lane>>4)*4 + j ----
    float* Yg = y + (size_t)g * T_ * N_;
#pragma unroll
    for (int n = 0; n < 4; ++n) {
        const int col = n0 + wcol + n * 16 + l15;
        const float bv = bias[g * N_ + col];
#pragma unroll
        for (int m = 0; m < 8; ++m) {
            const int r0 = t0 + wrow + m * 16 + lhi * 4;
#pragma unroll
            for (int j = 0; j < 4; ++j)
                Yg[(size_t)(r0 + j) * N_ + col] = acc[m][n][j] + bv;
        }
    }
}

// ---------------------------------------------------------------------------
extern "C" void kernel_launch(void* const* d_in, const int* in_sizes, int n_in,
                              void* d_out, int out_size, void* d_ws, size_t ws_size,
                              hipStream_t stream)
{
    const float* xs     = (const float*)d_in[0];
    const float* weight = (const float*)d_in[1];
    const float* scale  = (const float*)d_in[2];
    const float* bias   = (const float*)d_in[3];
    float* y = (float*)d_out;

    uint8_t* xq8   = (uint8_t*)d_ws;                        // 58,720,256 B
    float*   ascl  = (float*)((char*)d_ws + 58720256);      //  1,835,008 B
    uint8_t* wq8   = (uint8_t*)((char*)d_ws + 60555264);    // 117,440,512 B

    // 1) act quant: G*T*KB blocks of 128, 8 per 256-thread WG
    act_quant_kernel<<<(G_ * T_ * KB_) / 8, 256, 0, stream>>>(xs, xq8, ascl);

    // 2) weight recode fp32->fp8 bytes: 16 elems/thread
    wrecode_kernel<<<(int)(((size_t)G_ * N_ * K_ / 16) / 256), 256, 0, stream>>>(
        weight, wq8);

    // 3) blockwise-fp8 grouped GEMM
    gemm_fp8_kernel<<<256, 512, 0, stream>>>(xq8, wq8, ascl, scale, bias, y);
}